// Round 9
// baseline (226.230 us; speedup 1.0000x reference)
//
#include <hip/hip_runtime.h>

#define N_NODES 100000
#define N_EDGES 1600000
#define NG 64
#define NC 8
#define HD 128

#define BUCKET_SHIFT 8
#define NB ((N_NODES + 255) >> 8)   /* 391 buckets of 256 nodes */
#define NCHUNK 256
#define EPC (N_EDGES / NCHUNK)      /* 6250 edges per chunk */

typedef __attribute__((ext_vector_type(8))) __bf16 bf16x8;
typedef __attribute__((ext_vector_type(4))) float f32x4;
typedef __attribute__((ext_vector_type(2))) float f32x2;

#if defined(__has_builtin)
#if __has_builtin(__builtin_amdgcn_cvt_pk_f32_fp8)
#define HAVE_FP8_CVT 1
#endif
#endif

// e4m3fn encode (input >= 0 after relu); flush denormals (<2^-6) to 0.
__device__ inline unsigned int f32_to_e4m3(float v) {
  unsigned int b = __float_as_uint(v);
  b += 0x00080000u;                 // round mantissa to 3 bits
  unsigned int e = b >> 23;
  if (e < 121) return 0u;
  unsigned int q = (e > 135) ? 0x7Eu : (((e - 120) << 3) | ((b >> 20) & 7u));
  return q > 0x7Eu ? 0x7Eu : q;
}

__device__ inline float e4m3f(unsigned int t) {
  unsigned int e = (t >> 3) & 0xFu;
  unsigned int r = ((t & 0x80u) << 24) | ((e + 120u) << 23) | ((t & 7u) << 20);
  return e ? __uint_as_float(r) : 0.f;
}

// ---------------- fused init: zero g, build Wc, pack xs ----------------

__global__ void init_k(const float* __restrict__ x, const float* __restrict__ Wrel2,
                       const float* __restrict__ Wroot2, float4* __restrict__ xs4,
                       __bf16* __restrict__ Wc, unsigned int* __restrict__ g) {
  int i = blockIdx.x * 256 + threadIdx.x;
  if (i < 64 * 256) g[i] = 0u;
  if (i < 32768) {
    int h = i >> 8, k = i & 255;
    float v = (k < 128) ? Wrel2[h * 128 + k] : Wroot2[h * 128 + (k - 128)];
    Wc[i] = (__bf16)v;
  }
  if (i < N_NODES) {
    const float* xp = x + (size_t)i * 5;
    xs4[i] = make_float4(xp[2], xp[3], xp[4], 0.f);
  }
}

// ---------------- CSR build via two-level counting sort ----------------
// pairs packed as (src << 8) | local_dst

__global__ void bin_hist_k(const int* __restrict__ dst, int* __restrict__ hist) {
  __shared__ int lh[NB];
  int c = blockIdx.x, t = threadIdx.x;
  for (int b = t; b < NB; b += 256) lh[b] = 0;
  __syncthreads();
  int e0 = c * EPC;
  for (int i = t; i < EPC; i += 256) atomicAdd(&lh[dst[e0 + i] >> BUCKET_SHIFT], 1);
  __syncthreads();
  for (int b = t; b < NB; b += 256) hist[c * NB + b] = lh[b];
}

// per-bucket totals, parallel over buckets (replaces serial single-block base_k)

__global__ void bucket_sum_k(const int* __restrict__ hist, int* __restrict__ tot) {
  __shared__ int ws[4];
  int b = blockIdx.x, t = threadIdx.x, lane = t & 63, wid = t >> 6;
  int v = hist[t * NB + b];
#pragma unroll
  for (int off = 1; off < 64; off <<= 1) v += __shfl_xor(v, off);
  if (lane == 0) ws[wid] = v;
  __syncthreads();
  if (t == 0) tot[b] = ws[0] + ws[1] + ws[2] + ws[3];
}

__launch_bounds__(512)
__global__ void scan391_k(const int* __restrict__ tot, int* __restrict__ bucket_base,
                          int* __restrict__ row_ptr) {
  __shared__ int sm[512];
  int t = threadIdx.x;
  int s = (t < NB) ? tot[t] : 0;
  sm[t] = s;
  __syncthreads();
  for (int off = 1; off < 512; off <<= 1) {
    int v = (t >= off) ? sm[t - off] : 0;
    __syncthreads();
    sm[t] += v;
    __syncthreads();
  }
  if (t < NB) bucket_base[t] = sm[t] - s;
  if (t == 0) { bucket_base[NB] = N_EDGES; row_ptr[N_NODES] = N_EDGES; }
}

__global__ void chunk_scan_k(int* __restrict__ hist, const int* __restrict__ bucket_base) {
  int b = blockIdx.x, lane = threadIdx.x;
  int carry = bucket_base[b];
#pragma unroll
  for (int it = 0; it < NCHUNK / 64; it++) {
    int c = it * 64 + lane;
    int v = hist[c * NB + b];
    int s = v;
#pragma unroll
    for (int off = 1; off < 64; off <<= 1) {
      int u = __shfl_up(s, off);
      if (lane >= off) s += u;
    }
    hist[c * NB + b] = carry + s - v;
    carry += __shfl(s, 63);
  }
}

__global__ void scatter_k(const int* __restrict__ src, const int* __restrict__ dst,
                          const int* __restrict__ hist, unsigned int* __restrict__ pairs) {
  __shared__ int loff[NB];
  int c = blockIdx.x, t = threadIdx.x;
  for (int b = t; b < NB; b += 256) loff[b] = hist[c * NB + b];
  __syncthreads();
  int e0 = c * EPC;
  for (int i = t; i < EPC; i += 256) {
    int d = dst[e0 + i], s = src[e0 + i];
    int pos = atomicAdd(&loff[d >> BUCKET_SHIFT], 1);
    pairs[pos] = ((unsigned int)s << 8) | (unsigned int)(d & 255);
  }
}

__global__ void bucket_csr_k(const unsigned int* __restrict__ pairs,
                             const int* __restrict__ bucket_base,
                             int* __restrict__ row_ptr, int* __restrict__ csr) {
  __shared__ int cnt[256];
  __shared__ int start[256];
  __shared__ int wsum[4];
  int b = blockIdx.x, t = threadIdx.x, lane = t & 63, wid = t >> 6;
  int nb0 = b << BUCKET_SHIFT;
  int beg = bucket_base[b], end = bucket_base[b + 1];
  cnt[t] = 0;
  __syncthreads();
  for (int i = beg + t; i < end; i += 256) atomicAdd(&cnt[pairs[i] & 255u], 1);
  __syncthreads();
  int v = cnt[t];
  int s = v;
#pragma unroll
  for (int off = 1; off < 64; off <<= 1) {
    int u = __shfl_up(s, off);
    if (lane >= off) s += u;
  }
  if (lane == 63) wsum[wid] = s;
  __syncthreads();
  if (t == 0) {
    int a = 0;
    for (int j = 0; j < 4; j++) { int x = wsum[j]; wsum[j] = a; a += x; }
  }
  __syncthreads();
  int excl = wsum[wid] + s - v;
  start[t] = excl;
  if (nb0 + t < N_NODES) row_ptr[nb0 + t] = beg + excl;
  cnt[t] = 0;
  __syncthreads();
  for (int i = beg + t; i < end; i += 256) {
    unsigned int p = pairs[i];
    int li = p & 255u;
    int pos = beg + start[li] + atomicAdd(&cnt[li], 1);
    csr[pos] = (int)(p >> 8);
  }
}

// ---------------- conv1: float4 gather + butterfly; writes bf16 x1 AND fp8 x1q ----------------

__global__ void conv1_k(const float4* __restrict__ xs4, const int* __restrict__ row_ptr,
                        const int* __restrict__ csr, const float* __restrict__ Wroot1,
                        const float* __restrict__ Wrel1, const float* __restrict__ brel1,
                        __bf16* __restrict__ xcat, unsigned char* __restrict__ x1q) {
  int node = blockIdx.x * 4 + (threadIdx.x >> 6);
  if (node >= N_NODES) return;
  int lane = threadIdx.x & 63;
  int beg = row_ptr[node], end = row_ptr[node + 1];
  float a0 = 0.f, a1 = 0.f, a2 = 0.f;
  for (int e = beg + lane; e < end; e += 64) {
    float4 v = xs4[csr[e]];
    a0 += v.x; a1 += v.y; a2 += v.z;
  }
#pragma unroll
  for (int m = 1; m < 64; m <<= 1) {
    a0 += __shfl_xor(a0, m);
    a1 += __shfl_xor(a1, m);
    a2 += __shfl_xor(a2, m);
  }
  float4 rv = xs4[node];
  __bf16* orow = xcat + (size_t)node * 256 + 128;
  unsigned char* qrow = x1q + (size_t)node * 128;
#pragma unroll
  for (int hh = 0; hh < 2; hh++) {
    int h = lane + hh * 64;
    float v = brel1[h]
            + a0 * Wrel1[h * 3 + 0] + a1 * Wrel1[h * 3 + 1] + a2 * Wrel1[h * 3 + 2]
            + rv.x * Wroot1[h * 3 + 0] + rv.y * Wroot1[h * 3 + 1] + rv.z * Wroot1[h * 3 + 2];
    v = fmaxf(v, 0.f);
    orow[h] = (__bf16)v;
    qrow[h] = (unsigned char)f32_to_e4m3(v);
  }
}

// ---------------- agg2: fp8 gather (128B rows), 8 edges in flight ----------------

#ifdef HAVE_FP8_CVT
#define ACCD(dw, base) { f32x2 lo_ = __builtin_amdgcn_cvt_pk_f32_fp8((dw), 0); \
                         f32x2 hi_ = __builtin_amdgcn_cvt_pk_f32_fp8((dw), 1); \
                         acc[(base)+0] += lo_[0]; acc[(base)+1] += lo_[1];     \
                         acc[(base)+2] += hi_[0]; acc[(base)+3] += hi_[1]; }
#else
#define ACCD(dw, base) { acc[(base)+0] += e4m3f((dw) & 0xFFu);        \
                         acc[(base)+1] += e4m3f(((dw) >> 8) & 0xFFu); \
                         acc[(base)+2] += e4m3f(((dw) >> 16) & 0xFFu);\
                         acc[(base)+3] += e4m3f((dw) >> 24); }
#endif
#define ACCQ(u) { ACCD((u).x, 0) ACCD((u).y, 4) ACCD((u).z, 8) ACCD((u).w, 12) }
#define LDQ(s) (*((const uint4*)(x1q + (size_t)(s) * 128) + f))

__global__ void agg2_k(const int* __restrict__ row_ptr, const int* __restrict__ csr,
                       const unsigned char* __restrict__ x1q, __bf16* xcat) {
  int node = blockIdx.x * 4 + (threadIdx.x >> 6);
  if (node >= N_NODES) return;
  int lane = threadIdx.x & 63;
  int g = lane >> 3, f = lane & 7;   // g: edge slot (8), f: 16B chunk of 128B fp8 row
  int beg = row_ptr[node], end = row_ptr[node + 1];
  int deg = end - beg;
  int idx = (lane < deg) ? csr[beg + lane] : 0;
  float acc[16];
#pragma unroll
  for (int k = 0; k < 16; k++) acc[k] = 0.f;
  int dmain = deg < 64 ? deg : 64;
  int j = 0;
  for (; j + 16 <= dmain; j += 16) {   // 8+8 edges, 2 loads in flight per lane
    int s0 = __shfl(idx, j + g);
    int s1 = __shfl(idx, j + 8 + g);
    uint4 u0 = LDQ(s0);
    uint4 u1 = LDQ(s1);
    ACCQ(u0) ACCQ(u1)
  }
  if (j + 8 <= dmain) {
    int s0 = __shfl(idx, j + g);
    uint4 u0 = LDQ(s0);
    ACCQ(u0)
    j += 8;
  }
  {
    int rem = dmain - j;                 // 0..7 leftover edges
    int s0 = __shfl(idx, j + (g < rem ? g : 0));
    if (g < rem) {
      uint4 u0 = LDQ(s0);
      ACCQ(u0)
    }
  }
  for (int e = beg + 64; e < end; e += 8) {   // rare deg>64 tail
    int m = end - e;
    int s0 = csr[e + (g < m ? g : 0)];
    if (g < m) {
      uint4 u0 = LDQ(s0);
      ACCQ(u0)
    }
  }
#pragma unroll
  for (int k = 0; k < 16; k++) {   // reduce across the 8 edge-groups (lane bits 3,4,5)
    acc[k] += __shfl_xor(acc[k], 8);
    acc[k] += __shfl_xor(acc[k], 16);
    acc[k] += __shfl_xor(acc[k], 32);
  }
  // write 256B bf16 row: lane L<16 stores features 8L..8L+7 (16B).
  // feature 8L+jj lives at source lane fsel=L>>1, acc[(L&1)*8+jj].
  int L = lane, fsel = L >> 1, half = L & 1;
  float vals[8];
#pragma unroll
  for (int jj = 0; jj < 8; jj++) {
    float va = __shfl(acc[jj], fsel);
    float vb = __shfl(acc[8 + jj], fsel);
    vals[jj] = half ? vb : va;
  }
  if (L < 16) {
    uint4 o;
    o.x = (__float_as_uint((float)(__bf16)vals[0]) >> 16) | (__float_as_uint((float)(__bf16)vals[1]) & 0xffff0000u);
    o.y = (__float_as_uint((float)(__bf16)vals[2]) >> 16) | (__float_as_uint((float)(__bf16)vals[3]) & 0xffff0000u);
    o.z = (__float_as_uint((float)(__bf16)vals[4]) >> 16) | (__float_as_uint((float)(__bf16)vals[5]) & 0xffff0000u);
    o.w = (__float_as_uint((float)(__bf16)vals[6]) >> 16) | (__float_as_uint((float)(__bf16)vals[7]) & 0xffff0000u);
    *((uint4*)(xcat + (size_t)node * 256) + L) = o;
  }
}

// ---------------- conv2 GEMM: B staged in LDS (XOR-swizzled), fused segment-max ----------------

__launch_bounds__(512, 4)
__global__ void gemm2_k(const __bf16* __restrict__ xcat, const __bf16* __restrict__ Wc,
                        const float* __restrict__ brel2, const int* __restrict__ batch,
                        unsigned int* __restrict__ gout) {
  __shared__ char Blds[128 * 256 * 2];   // 64 KB
  int t = threadIdx.x;
  for (int i = t; i < 4096; i += 512) {
    uint4 v = ((const uint4*)Wc)[i];
    int byte = i * 16;
    int sw = byte ^ (((byte >> 9) & 7) << 4);
    *(uint4*)(Blds + sw) = v;
  }
  __syncthreads();
  int wid = t >> 6, lane = t & 63;
  int nb = (blockIdx.x * 8 + wid) * 32;
  if (nb >= N_NODES) return;
  int r = lane & 15, ko = lane >> 4;
  const __bf16* arow0 = xcat + (size_t)(nb + r) * 256 + ko * 8;
  const __bf16* arow1 = arow0 + 16 * 256;
  f32x4 acc0[8], acc1[8];
#pragma unroll
  for (int i = 0; i < 8; i++) {
    acc0[i] = (f32x4){0.f, 0.f, 0.f, 0.f};
    acc1[i] = (f32x4){0.f, 0.f, 0.f, 0.f};
  }
#pragma unroll
  for (int kb = 0; kb < 256; kb += 32) {
    bf16x8 a0 = *(const bf16x8*)(arow0 + kb);
    bf16x8 a1 = *(const bf16x8*)(arow1 + kb);
#pragma unroll
    for (int ht = 0; ht < 8; ht++) {
      int h = ht * 16 + r;
      int byte = h * 512 + ko * 16 + kb * 2;
      bf16x8 b = *(const bf16x8*)(Blds + (byte ^ ((r & 7) << 4)));
      acc0[ht] = __builtin_amdgcn_mfma_f32_16x16x32_bf16(a0, b, acc0[ht], 0, 0, 0);
      acc1[ht] = __builtin_amdgcn_mfma_f32_16x16x32_bf16(a1, b, acc1[ht], 0, 0, 0);
    }
  }
  int gfirst = batch[nb], glast = batch[nb + 31];
  if (gfirst == glast) {
    unsigned int* gp = gout + gfirst * 256 + 128;
#pragma unroll
    for (int ht = 0; ht < 8; ht++) {
      float bias = brel2[ht * 16 + r];
      float m = 0.f;
#pragma unroll
      for (int rr = 0; rr < 4; rr++) {
        m = fmaxf(m, acc0[ht][rr] + bias);
        m = fmaxf(m, acc1[ht][rr] + bias);
      }
      m = fmaxf(m, __shfl_xor(m, 16));
      m = fmaxf(m, __shfl_xor(m, 32));
      if (ko == 0) atomicMax(&gp[ht * 16 + r], __float_as_uint(m));
    }
  } else {
    int g0[4], g1[4];
#pragma unroll
    for (int rr = 0; rr < 4; rr++) {
      g0[rr] = batch[nb + ko * 4 + rr];
      g1[rr] = batch[nb + 16 + ko * 4 + rr];
    }
#pragma unroll
    for (int ht = 0; ht < 8; ht++) {
      int h = ht * 16 + r;
      float bias = brel2[h];
#pragma unroll
      for (int rr = 0; rr < 4; rr++) {
        atomicMax(&gout[g0[rr] * 256 + 128 + h],
                  __float_as_uint(fmaxf(acc0[ht][rr] + bias, 0.f)));
        atomicMax(&gout[g1[rr] * 256 + 128 + h],
                  __float_as_uint(fmaxf(acc1[ht][rr] + bias, 0.f)));
      }
    }
  }
}

// ---------------- segment_max over x1 half into g[grp][0..127] ----------------

__global__ void segmax1_k(const __bf16* __restrict__ xcat, const int* __restrict__ batch,
                          unsigned int* __restrict__ g) {
  int t = threadIdx.x;
  int f = t & 63;
  int s = t >> 6;
  int n0 = blockIdx.x * 256;
  float m0 = 0.f, m1 = 0.f;
  int cur = -1;
  int n1 = n0 + 256 < N_NODES ? n0 + 256 : N_NODES;
  for (int n = n0 + s; n < n1; n += 4) {
    int b = batch[n];
    if (b != cur) {
      if (cur >= 0) {
        atomicMax(&g[cur * 256 + 2 * f], __float_as_uint(m0));
        atomicMax(&g[cur * 256 + 2 * f + 1], __float_as_uint(m1));
      }
      cur = b; m0 = 0.f; m1 = 0.f;
    }
    unsigned int u = ((const unsigned int*)(xcat + (size_t)n * 256 + 128))[f];
    m0 = fmaxf(m0, __uint_as_float(u << 16));
    m1 = fmaxf(m1, __uint_as_float(u & 0xffff0000u));
  }
  if (cur >= 0) {
    atomicMax(&g[cur * 256 + 2 * f], __float_as_uint(m0));
    atomicMax(&g[cur * 256 + 2 * f + 1], __float_as_uint(m1));
  }
}

// ---------------- MLP head ----------------

__global__ void head1_k(const float* __restrict__ g, const float* __restrict__ exinfo,
                        const float* __restrict__ W1, const float* __restrict__ b1,
                        float* __restrict__ g1) {
  int gg = blockIdx.x;
  int t = threadIdx.x;
  int c = t >> 2, q = t & 3;
  const float* w = W1 + c * 266;
  const float* gr = g + gg * 256;
  float s = 0.f;
  for (int k = q * 64; k < q * 64 + 64; k++) s += gr[k] * w[k];
  if (q == 0) {
    const float* er = exinfo + gg * 10;
    for (int k = 0; k < 10; k++) s += er[k] * w[256 + k];
    s += b1[c];
  }
  s += __shfl_xor(s, 1);
  s += __shfl_xor(s, 2);
  if (q == 0) g1[gg * 64 + c] = fmaxf(s, 0.f);
}

__global__ void head2_k(const float* __restrict__ g1, const float* __restrict__ W2,
                        const float* __restrict__ b2, const float* __restrict__ W3,
                        const float* __restrict__ b3, float* __restrict__ out) {
  __shared__ float s1[64 * 64];
  __shared__ float s2[64 * 32];
  int t = threadIdx.x;
  for (int i = t; i < 4096; i += 256) s1[i] = g1[i];
  __syncthreads();
  for (int o = t; o < 2048; o += 256) {
    int r = o >> 5, c = o & 31;
    float s = b2[c];
    for (int k = 0; k < 64; k++) s += s1[r * 64 + k] * W2[c * 64 + k];
    s2[r * 32 + c] = fmaxf(s, 0.f);
  }
  __syncthreads();
  if (t < 64) {
    float lg[8];
#pragma unroll
    for (int c = 0; c < 8; c++) {
      float s = b3[c];
      for (int k = 0; k < 32; k++) s += s2[t * 32 + k] * W3[c * 32 + k];
      lg[c] = s;
    }
    float mx = lg[0];
#pragma unroll
    for (int c = 1; c < 8; c++) mx = fmaxf(mx, lg[c]);
    float se = 0.f;
#pragma unroll
    for (int c = 0; c < 8; c++) se += expf(lg[c] - mx);
    float lse = mx + logf(se);
#pragma unroll
    for (int c = 0; c < 8; c++) out[t * 8 + c] = lg[c] - lse;
  }
}

// ---------------- launch ----------------

extern "C" void kernel_launch(void* const* d_in, const int* in_sizes, int n_in,
                              void* d_out, int out_size, void* d_ws, size_t ws_size,
                              hipStream_t stream) {
  const float* x      = (const float*)d_in[0];
  const int*   edge   = (const int*)d_in[1];
  const int*   batch  = (const int*)d_in[2];
  const float* exinfo = (const float*)d_in[3];
  const float* Wroot1 = (const float*)d_in[4];
  const float* Wrel1  = (const float*)d_in[5];
  const float* brel1  = (const float*)d_in[6];
  const float* Wroot2 = (const float*)d_in[7];
  const float* Wrel2  = (const float*)d_in[8];
  const float* brel2  = (const float*)d_in[9];
  const float* W1     = (const float*)d_in[10];
  const float* b1     = (const float*)d_in[11];
  const float* W2     = (const float*)d_in[12];
  const float* b2     = (const float*)d_in[13];
  const float* W3     = (const float*)d_in[14];
  const float* b3     = (const float*)d_in[15];
  const int* src = edge;
  const int* dst = edge + N_EDGES;

  char* p = (char*)d_ws;
  auto alloc = [&](size_t bytes) {
    char* q = p;
    p += (bytes + 511) & ~(size_t)511;
    return (void*)q;
  };
  __bf16*        Wc          = (__bf16*)alloc(128 * 256 * 2);
  unsigned int*  g           = (unsigned int*)alloc(64 * 256 * 4);
  float*         g1          = (float*)alloc(64 * 64 * 4);
  float4*        xs4         = (float4*)alloc((size_t)N_NODES * 16);
  int*           hist        = (int*)alloc((size_t)NCHUNK * NB * 4);
  int*           btot        = (int*)alloc((size_t)NB * 4);
  int*           bucket_base = (int*)alloc((size_t)(NB + 1) * 4);
  int*           row_ptr     = (int*)alloc((size_t)(N_NODES + 1) * 4);
  int*           csr         = (int*)alloc((size_t)N_EDGES * 4);
  __bf16*        xcat        = (__bf16*)alloc((size_t)N_NODES * 256 * 2);
  unsigned char* x1q         = (unsigned char*)alloc((size_t)N_NODES * 128);
  unsigned int*  pairs       = (unsigned int*)alloc((size_t)N_EDGES * 4);

  init_k<<<NB, 256, 0, stream>>>(x, Wrel2, Wroot2, xs4, Wc, g);
  bin_hist_k<<<NCHUNK, 256, 0, stream>>>(dst, hist);
  bucket_sum_k<<<NB, 256, 0, stream>>>(hist, btot);
  scan391_k<<<1, 512, 0, stream>>>(btot, bucket_base, row_ptr);
  chunk_scan_k<<<NB, 64, 0, stream>>>(hist, bucket_base);
  scatter_k<<<NCHUNK, 256, 0, stream>>>(src, dst, hist, pairs);
  bucket_csr_k<<<NB, 256, 0, stream>>>(pairs, bucket_base, row_ptr, csr);
  conv1_k<<<25000, 256, 0, stream>>>(xs4, row_ptr, csr, Wroot1, Wrel1, brel1, xcat, x1q);
  agg2_k<<<25000, 256, 0, stream>>>(row_ptr, csr, x1q, xcat);
  gemm2_k<<<391, 512, 0, stream>>>(xcat, Wc, brel2, batch, g);
  segmax1_k<<<NB, 256, 0, stream>>>(xcat, batch, g);
  head1_k<<<64, 256, 0, stream>>>((const float*)g, exinfo, W1, b1, g1);
  head2_k<<<1, 256, 0, stream>>>(g1, W2, b2, W3, b3, (float*)d_out);
}

// Round 10
// 206.541 us; speedup vs baseline: 1.0953x; 1.0953x over previous
//
#include <hip/hip_runtime.h>

#define N_NODES 100000
#define N_EDGES 1600000
#define NG 64
#define NC 8
#define HD 128

#define BUCKET_SHIFT 8
#define NB ((N_NODES + 255) >> 8)   /* 391 buckets of 256 nodes */
#define NCHUNK 256
#define EPC (N_EDGES / NCHUNK)      /* 6250 edges per chunk */

typedef __attribute__((ext_vector_type(8))) __bf16 bf16x8;
typedef __attribute__((ext_vector_type(4))) float f32x4;
typedef __attribute__((ext_vector_type(2))) float f32x2;

// ---------------- fused: init (zero g, build Wc, pack xs) + edge histogram ----------------
// blocks 0..NCHUNK-1: per-chunk histogram.  blocks NCHUNK..NCHUNK+NB-1: init work.

__global__ void hist_init_k(const int* __restrict__ dst, int* __restrict__ hist,
                            const float* __restrict__ x, const float* __restrict__ Wrel2,
                            const float* __restrict__ Wroot2, float4* __restrict__ xs4,
                            __bf16* __restrict__ Wc, unsigned int* __restrict__ g) {
  int t = threadIdx.x;
  if (blockIdx.x < NCHUNK) {
    __shared__ int lh[NB];
    int c = blockIdx.x;
    for (int b = t; b < NB; b += 256) lh[b] = 0;
    __syncthreads();
    int e0 = c * EPC;
    for (int i = t; i < EPC; i += 256) atomicAdd(&lh[dst[e0 + i] >> BUCKET_SHIFT], 1);
    __syncthreads();
    for (int b = t; b < NB; b += 256) hist[c * NB + b] = lh[b];
  } else {
    int i = (blockIdx.x - NCHUNK) * 256 + t;
    if (i < 64 * 256) g[i] = 0u;
    if (i < 32768) {
      int h = i >> 8, k = i & 255;
      float v = (k < 128) ? Wrel2[h * 128 + k] : Wroot2[h * 128 + (k - 128)];
      Wc[i] = (__bf16)v;
    }
    if (i < N_NODES) {
      const float* xp = x + (size_t)i * 5;
      xs4[i] = make_float4(xp[2], xp[3], xp[4], 0.f);
    }
  }
}

// ---------------- bucket totals + exclusive scan (single 512-thread block) ----------------

__launch_bounds__(512)
__global__ void sum_scan_k(const int* __restrict__ hist, int* __restrict__ bucket_base,
                           int* __restrict__ row_ptr) {
  __shared__ int sm[512];
  int t = threadIdx.x;
  int s = 0;
  if (t < NB) {
#pragma unroll 8
    for (int c = 0; c < NCHUNK; c++) s += hist[c * NB + t];
  }
  sm[t] = s;
  __syncthreads();
  for (int off = 1; off < 512; off <<= 1) {
    int v = (t >= off) ? sm[t - off] : 0;
    __syncthreads();
    sm[t] += v;
    __syncthreads();
  }
  if (t < NB) bucket_base[t] = sm[t] - s;
  if (t == 0) { bucket_base[NB] = N_EDGES; row_ptr[N_NODES] = N_EDGES; }
}

__global__ void chunk_scan_k(int* __restrict__ hist, const int* __restrict__ bucket_base) {
  int b = blockIdx.x, lane = threadIdx.x;
  int carry = bucket_base[b];
#pragma unroll
  for (int it = 0; it < NCHUNK / 64; it++) {
    int c = it * 64 + lane;
    int v = hist[c * NB + b];
    int s = v;
#pragma unroll
    for (int off = 1; off < 64; off <<= 1) {
      int u = __shfl_up(s, off);
      if (lane >= off) s += u;
    }
    hist[c * NB + b] = carry + s - v;
    carry += __shfl(s, 63);
  }
}

__global__ void scatter_k(const int* __restrict__ src, const int* __restrict__ dst,
                          const int* __restrict__ hist, unsigned int* __restrict__ pairs) {
  __shared__ int loff[NB];
  int c = blockIdx.x, t = threadIdx.x;
  for (int b = t; b < NB; b += 256) loff[b] = hist[c * NB + b];
  __syncthreads();
  int e0 = c * EPC;
  for (int i = t; i < EPC; i += 256) {
    int d = dst[e0 + i], s = src[e0 + i];
    int pos = atomicAdd(&loff[d >> BUCKET_SHIFT], 1);
    pairs[pos] = ((unsigned int)s << 8) | (unsigned int)(d & 255);
  }
}

__global__ void bucket_csr_k(const unsigned int* __restrict__ pairs,
                             const int* __restrict__ bucket_base,
                             int* __restrict__ row_ptr, int* __restrict__ csr) {
  __shared__ int cnt[256];
  __shared__ int start[256];
  __shared__ int wsum[4];
  int b = blockIdx.x, t = threadIdx.x, lane = t & 63, wid = t >> 6;
  int nb0 = b << BUCKET_SHIFT;
  int beg = bucket_base[b], end = bucket_base[b + 1];
  cnt[t] = 0;
  __syncthreads();
  for (int i = beg + t; i < end; i += 256) atomicAdd(&cnt[pairs[i] & 255u], 1);
  __syncthreads();
  int v = cnt[t];
  int s = v;
#pragma unroll
  for (int off = 1; off < 64; off <<= 1) {
    int u = __shfl_up(s, off);
    if (lane >= off) s += u;
  }
  if (lane == 63) wsum[wid] = s;
  __syncthreads();
  if (t == 0) {
    int a = 0;
    for (int j = 0; j < 4; j++) { int x = wsum[j]; wsum[j] = a; a += x; }
  }
  __syncthreads();
  int excl = wsum[wid] + s - v;
  start[t] = excl;
  if (nb0 + t < N_NODES) row_ptr[nb0 + t] = beg + excl;
  cnt[t] = 0;
  __syncthreads();
  for (int i = beg + t; i < end; i += 256) {
    unsigned int p = pairs[i];
    int li = p & 255u;
    int pos = beg + start[li] + atomicAdd(&cnt[li], 1);
    csr[pos] = (int)(p >> 8);
  }
}

// ---------------- conv1: float4 gather + butterfly reduce ----------------

__global__ void conv1_k(const float4* __restrict__ xs4, const int* __restrict__ row_ptr,
                        const int* __restrict__ csr, const float* __restrict__ Wroot1,
                        const float* __restrict__ Wrel1, const float* __restrict__ brel1,
                        __bf16* __restrict__ xcat) {
  int node = blockIdx.x * 4 + (threadIdx.x >> 6);
  if (node >= N_NODES) return;
  int lane = threadIdx.x & 63;
  int beg = row_ptr[node], end = row_ptr[node + 1];
  float a0 = 0.f, a1 = 0.f, a2 = 0.f;
  for (int e = beg + lane; e < end; e += 64) {
    float4 v = xs4[csr[e]];
    a0 += v.x; a1 += v.y; a2 += v.z;
  }
#pragma unroll
  for (int m = 1; m < 64; m <<= 1) {
    a0 += __shfl_xor(a0, m);
    a1 += __shfl_xor(a1, m);
    a2 += __shfl_xor(a2, m);
  }
  float4 rv = xs4[node];
  __bf16* orow = xcat + (size_t)node * 256 + 128;
#pragma unroll
  for (int hh = 0; hh < 2; hh++) {
    int h = lane + hh * 64;
    float v = brel1[h]
            + a0 * Wrel1[h * 3 + 0] + a1 * Wrel1[h * 3 + 1] + a2 * Wrel1[h * 3 + 2]
            + rv.x * Wroot1[h * 3 + 0] + rv.y * Wroot1[h * 3 + 1] + rv.z * Wroot1[h * 3 + 2];
    orow[h] = (__bf16)fmaxf(v, 0.f);
  }
}

// ---------------- agg2: bf16 gather, 16 edges (4 dwordx4) in flight (proven R8 form) ----------------

#define LDROW(s) (*((const uint4*)(xcat + (size_t)(s) * 256 + 128) + f))
#define ACC8(u) \
  acc2[0] += (f32x2){__uint_as_float((u).x << 16), __uint_as_float((u).x & 0xffff0000u)}; \
  acc2[1] += (f32x2){__uint_as_float((u).y << 16), __uint_as_float((u).y & 0xffff0000u)}; \
  acc2[2] += (f32x2){__uint_as_float((u).z << 16), __uint_as_float((u).z & 0xffff0000u)}; \
  acc2[3] += (f32x2){__uint_as_float((u).w << 16), __uint_as_float((u).w & 0xffff0000u)};

__global__ void agg2_k(const int* __restrict__ row_ptr, const int* __restrict__ csr,
                       __bf16* xcat) {
  int node = blockIdx.x * 4 + (threadIdx.x >> 6);
  if (node >= N_NODES) return;
  int lane = threadIdx.x & 63;
  int g = lane >> 4, f = lane & 15;
  int beg = row_ptr[node], end = row_ptr[node + 1];
  int deg = end - beg;
  int idx = (lane < deg) ? csr[beg + lane] : 0;
  f32x2 acc2[4];
#pragma unroll
  for (int k = 0; k < 4; k++) acc2[k] = (f32x2){0.f, 0.f};
  int dmain = deg < 64 ? deg : 64;
  int j = 0;
  for (; j + 16 <= dmain; j += 16) {
    int s0 = __shfl(idx, j + g);
    int s1 = __shfl(idx, j + 4 + g);
    int s2 = __shfl(idx, j + 8 + g);
    int s3 = __shfl(idx, j + 12 + g);
    uint4 u0 = LDROW(s0);
    uint4 u1 = LDROW(s1);
    uint4 u2 = LDROW(s2);
    uint4 u3 = LDROW(s3);
    ACC8(u0) ACC8(u1) ACC8(u2) ACC8(u3)
  }
  if (j + 8 <= dmain) {
    int s0 = __shfl(idx, j + g);
    int s1 = __shfl(idx, j + 4 + g);
    uint4 u0 = LDROW(s0);
    uint4 u1 = LDROW(s1);
    ACC8(u0) ACC8(u1)
    j += 8;
  }
  if (j + 4 <= dmain) {
    int s0 = __shfl(idx, j + g);
    uint4 u0 = LDROW(s0);
    ACC8(u0)
    j += 4;
  }
  {
    int rem = dmain - j;
    int s0 = __shfl(idx, j + (g < rem ? g : 0));
    if (g < rem) {
      uint4 u0 = LDROW(s0);
      ACC8(u0)
    }
  }
  for (int e = beg + 64; e < end; e += 4) {
    int m = end - e;
    int s0 = csr[e + (g < m ? g : 0)];
    if (g < m) {
      uint4 u0 = LDROW(s0);
      ACC8(u0)
    }
  }
#pragma unroll
  for (int k = 0; k < 4; k++) {
    acc2[k].x += __shfl_xor(acc2[k].x, 16);
    acc2[k].y += __shfl_xor(acc2[k].y, 16);
    acc2[k].x += __shfl_xor(acc2[k].x, 32);
    acc2[k].y += __shfl_xor(acc2[k].y, 32);
  }
  if (g == 0) {
    uint4 o;
    o.x = (__float_as_uint((float)(__bf16)acc2[0].x) >> 16) | (__float_as_uint((float)(__bf16)acc2[0].y) & 0xffff0000u);
    o.y = (__float_as_uint((float)(__bf16)acc2[1].x) >> 16) | (__float_as_uint((float)(__bf16)acc2[1].y) & 0xffff0000u);
    o.z = (__float_as_uint((float)(__bf16)acc2[2].x) >> 16) | (__float_as_uint((float)(__bf16)acc2[2].y) & 0xffff0000u);
    o.w = (__float_as_uint((float)(__bf16)acc2[3].x) >> 16) | (__float_as_uint((float)(__bf16)acc2[3].y) & 0xffff0000u);
    *((uint4*)(xcat + (size_t)node * 256) + f) = o;
  }
}

// ---------------- conv2 GEMM: B staged in LDS (XOR-swizzled), fused segment-max ----------------

__launch_bounds__(512, 4)
__global__ void gemm2_k(const __bf16* __restrict__ xcat, const __bf16* __restrict__ Wc,
                        const float* __restrict__ brel2, const int* __restrict__ batch,
                        unsigned int* __restrict__ gout) {
  __shared__ char Blds[128 * 256 * 2];   // 64 KB
  int t = threadIdx.x;
  for (int i = t; i < 4096; i += 512) {
    uint4 v = ((const uint4*)Wc)[i];
    int byte = i * 16;
    int sw = byte ^ (((byte >> 9) & 7) << 4);
    *(uint4*)(Blds + sw) = v;
  }
  __syncthreads();
  int wid = t >> 6, lane = t & 63;
  int nb = (blockIdx.x * 8 + wid) * 32;
  if (nb >= N_NODES) return;
  int r = lane & 15, ko = lane >> 4;
  const __bf16* arow0 = xcat + (size_t)(nb + r) * 256 + ko * 8;
  const __bf16* arow1 = arow0 + 16 * 256;
  f32x4 acc0[8], acc1[8];
#pragma unroll
  for (int i = 0; i < 8; i++) {
    acc0[i] = (f32x4){0.f, 0.f, 0.f, 0.f};
    acc1[i] = (f32x4){0.f, 0.f, 0.f, 0.f};
  }
#pragma unroll
  for (int kb = 0; kb < 256; kb += 32) {
    bf16x8 a0 = *(const bf16x8*)(arow0 + kb);
    bf16x8 a1 = *(const bf16x8*)(arow1 + kb);
#pragma unroll
    for (int ht = 0; ht < 8; ht++) {
      int h = ht * 16 + r;
      int byte = h * 512 + ko * 16 + kb * 2;
      bf16x8 b = *(const bf16x8*)(Blds + (byte ^ ((r & 7) << 4)));
      acc0[ht] = __builtin_amdgcn_mfma_f32_16x16x32_bf16(a0, b, acc0[ht], 0, 0, 0);
      acc1[ht] = __builtin_amdgcn_mfma_f32_16x16x32_bf16(a1, b, acc1[ht], 0, 0, 0);
    }
  }
  int gfirst = batch[nb], glast = batch[nb + 31];
  if (gfirst == glast) {
    unsigned int* gp = gout + gfirst * 256 + 128;
#pragma unroll
    for (int ht = 0; ht < 8; ht++) {
      float bias = brel2[ht * 16 + r];
      float m = 0.f;
#pragma unroll
      for (int rr = 0; rr < 4; rr++) {
        m = fmaxf(m, acc0[ht][rr] + bias);
        m = fmaxf(m, acc1[ht][rr] + bias);
      }
      m = fmaxf(m, __shfl_xor(m, 16));
      m = fmaxf(m, __shfl_xor(m, 32));
      if (ko == 0) atomicMax(&gp[ht * 16 + r], __float_as_uint(m));
    }
  } else {
    int g0[4], g1[4];
#pragma unroll
    for (int rr = 0; rr < 4; rr++) {
      g0[rr] = batch[nb + ko * 4 + rr];
      g1[rr] = batch[nb + 16 + ko * 4 + rr];
    }
#pragma unroll
    for (int ht = 0; ht < 8; ht++) {
      int h = ht * 16 + r;
      float bias = brel2[h];
#pragma unroll
      for (int rr = 0; rr < 4; rr++) {
        atomicMax(&gout[g0[rr] * 256 + 128 + h],
                  __float_as_uint(fmaxf(acc0[ht][rr] + bias, 0.f)));
        atomicMax(&gout[g1[rr] * 256 + 128 + h],
                  __float_as_uint(fmaxf(acc1[ht][rr] + bias, 0.f)));
      }
    }
  }
}

// ---------------- segment_max over x1 half into g[grp][0..127] ----------------

__global__ void segmax1_k(const __bf16* __restrict__ xcat, const int* __restrict__ batch,
                          unsigned int* __restrict__ g) {
  int t = threadIdx.x;
  int f = t & 63;
  int s = t >> 6;
  int n0 = blockIdx.x * 256;
  float m0 = 0.f, m1 = 0.f;
  int cur = -1;
  int n1 = n0 + 256 < N_NODES ? n0 + 256 : N_NODES;
  for (int n = n0 + s; n < n1; n += 4) {
    int b = batch[n];
    if (b != cur) {
      if (cur >= 0) {
        atomicMax(&g[cur * 256 + 2 * f], __float_as_uint(m0));
        atomicMax(&g[cur * 256 + 2 * f + 1], __float_as_uint(m1));
      }
      cur = b; m0 = 0.f; m1 = 0.f;
    }
    unsigned int u = ((const unsigned int*)(xcat + (size_t)n * 256 + 128))[f];
    m0 = fmaxf(m0, __uint_as_float(u << 16));
    m1 = fmaxf(m1, __uint_as_float(u & 0xffff0000u));
  }
  if (cur >= 0) {
    atomicMax(&g[cur * 256 + 2 * f], __float_as_uint(m0));
    atomicMax(&g[cur * 256 + 2 * f + 1], __float_as_uint(m1));
  }
}

// ---------------- MLP head ----------------

__global__ void head1_k(const float* __restrict__ g, const float* __restrict__ exinfo,
                        const float* __restrict__ W1, const float* __restrict__ b1,
                        float* __restrict__ g1) {
  int gg = blockIdx.x;
  int t = threadIdx.x;
  int c = t >> 2, q = t & 3;
  const float* w = W1 + c * 266;
  const float* gr = g + gg * 256;
  float s = 0.f;
  for (int k = q * 64; k < q * 64 + 64; k++) s += gr[k] * w[k];
  if (q == 0) {
    const float* er = exinfo + gg * 10;
    for (int k = 0; k < 10; k++) s += er[k] * w[256 + k];
    s += b1[c];
  }
  s += __shfl_xor(s, 1);
  s += __shfl_xor(s, 2);
  if (q == 0) g1[gg * 64 + c] = fmaxf(s, 0.f);
}

__global__ void head2_k(const float* __restrict__ g1, const float* __restrict__ W2,
                        const float* __restrict__ b2, const float* __restrict__ W3,
                        const float* __restrict__ b3, float* __restrict__ out) {
  __shared__ float s1[64 * 64];
  __shared__ float s2[64 * 32];
  int t = threadIdx.x;
  for (int i = t; i < 4096; i += 256) s1[i] = g1[i];
  __syncthreads();
  for (int o = t; o < 2048; o += 256) {
    int r = o >> 5, c = o & 31;
    float s = b2[c];
    for (int k = 0; k < 64; k++) s += s1[r * 64 + k] * W2[c * 64 + k];
    s2[r * 32 + c] = fmaxf(s, 0.f);
  }
  __syncthreads();
  if (t < 64) {
    float lg[8];
#pragma unroll
    for (int c = 0; c < 8; c++) {
      float s = b3[c];
      for (int k = 0; k < 32; k++) s += s2[t * 32 + k] * W3[c * 32 + k];
      lg[c] = s;
    }
    float mx = lg[0];
#pragma unroll
    for (int c = 1; c < 8; c++) mx = fmaxf(mx, lg[c]);
    float se = 0.f;
#pragma unroll
    for (int c = 0; c < 8; c++) se += expf(lg[c] - mx);
    float lse = mx + logf(se);
#pragma unroll
    for (int c = 0; c < 8; c++) out[t * 8 + c] = lg[c] - lse;
  }
}

// ---------------- launch ----------------

extern "C" void kernel_launch(void* const* d_in, const int* in_sizes, int n_in,
                              void* d_out, int out_size, void* d_ws, size_t ws_size,
                              hipStream_t stream) {
  const float* x      = (const float*)d_in[0];
  const int*   edge   = (const int*)d_in[1];
  const int*   batch  = (const int*)d_in[2];
  const float* exinfo = (const float*)d_in[3];
  const float* Wroot1 = (const float*)d_in[4];
  const float* Wrel1  = (const float*)d_in[5];
  const float* brel1  = (const float*)d_in[6];
  const float* Wroot2 = (const float*)d_in[7];
  const float* Wrel2  = (const float*)d_in[8];
  const float* brel2  = (const float*)d_in[9];
  const float* W1     = (const float*)d_in[10];
  const float* b1     = (const float*)d_in[11];
  const float* W2     = (const float*)d_in[12];
  const float* b2     = (const float*)d_in[13];
  const float* W3     = (const float*)d_in[14];
  const float* b3     = (const float*)d_in[15];
  const int* src = edge;
  const int* dst = edge + N_EDGES;

  char* p = (char*)d_ws;
  auto alloc = [&](size_t bytes) {
    char* q = p;
    p += (bytes + 511) & ~(size_t)511;
    return (void*)q;
  };
  __bf16*       Wc          = (__bf16*)alloc(128 * 256 * 2);
  unsigned int* g           = (unsigned int*)alloc(64 * 256 * 4);
  float*        g1          = (float*)alloc(64 * 64 * 4);
  float4*       xs4         = (float4*)alloc((size_t)N_NODES * 16);
  int*          hist        = (int*)alloc((size_t)NCHUNK * NB * 4);
  int*          bucket_base = (int*)alloc((size_t)(NB + 1) * 4);
  int*          row_ptr     = (int*)alloc((size_t)(N_NODES + 1) * 4);
  int*          csr         = (int*)alloc((size_t)N_EDGES * 4);
  __bf16*       xcat        = (__bf16*)alloc((size_t)N_NODES * 256 * 2);
  unsigned int* pairs       = (unsigned int*)alloc((size_t)N_EDGES * 4);

  hist_init_k<<<NCHUNK + NB, 256, 0, stream>>>(dst, hist, x, Wrel2, Wroot2, xs4, Wc, g);
  sum_scan_k<<<1, 512, 0, stream>>>(hist, bucket_base, row_ptr);
  chunk_scan_k<<<NB, 64, 0, stream>>>(hist, bucket_base);
  scatter_k<<<NCHUNK, 256, 0, stream>>>(src, dst, hist, pairs);
  bucket_csr_k<<<NB, 256, 0, stream>>>(pairs, bucket_base, row_ptr, csr);
  conv1_k<<<25000, 256, 0, stream>>>(xs4, row_ptr, csr, Wroot1, Wrel1, brel1, xcat);
  agg2_k<<<25000, 256, 0, stream>>>(row_ptr, csr, xcat);
  gemm2_k<<<391, 512, 0, stream>>>(xcat, Wc, brel2, batch, g);
  segmax1_k<<<NB, 256, 0, stream>>>(xcat, batch, g);
  head1_k<<<64, 256, 0, stream>>>((const float*)g, exinfo, W1, b1, g1);
  head2_k<<<1, 256, 0, stream>>>(g1, W2, b2, W3, b3, (float*)d_out);
}